// Round 4
// baseline (320.567 us; speedup 1.0000x reference)
//
#include <hip/hip_runtime.h>
#include <math.h>

#define D_DIM  2048
#define NE     64
#define NTOK   16384
#define TK     8
#define TOKB   64
#define NW     16          // waves per block (split-K 16)
#define KCW    16          // d per chunk per wave
#define NCHUNK 8           // 16 waves * 16 d * 8 chunks = 2048 d
#define GT     1024

#define OUT_I_OFF (NTOK * TK)
#define OUT_S_OFF (2 * NTOK * TK)

#define GLOBAL_AS __attribute__((address_space(1)))
#define LDS_AS    __attribute__((address_space(3)))

static __device__ __forceinline__ void async_copy16(const float* g, float* l) {
    __builtin_amdgcn_global_load_lds((const GLOBAL_AS void*)g, (LDS_AS void*)l, 16, 0, 0);
}

// LDS map (floats): staging wave wv: x at wv*2048 (1024), w at wv*2048+1024 (1024)  -> 32768
// reduction regions k=0..7: k*4352 + lane*68 + m (17408 B each)                     -> 34816
// score grid (post-reduction): offset 2*4352, 64 x 72                               (reuse)
__global__ __launch_bounds__(GT, 4) void gate_fused(
    const float* __restrict__ x, const float* __restrict__ w,
    const float* __restrict__ gb, float* __restrict__ out)
{
    __shared__ float lds[34816];

    const int tid  = threadIdx.x;
    const int lane = tid & 63;
    const int wv   = tid >> 6;        // 0..15
    const int tq   = lane >> 3;       // token octet
    const int eq   = lane & 7;        // expert octet
    const int tok0 = blockIdx.x * TOKB;

    float* xb = &lds[wv * 2048];
    float* wb = &lds[wv * 2048 + 1024];

    // compute-side read bases, one per logical quad dq; physical quad = dq ^ (octet&3)
    const float* xrd[4]; const float* wrd[4];
#pragma unroll
    for (int dq = 0; dq < 4; ++dq) {
        xrd[dq] = xb + tq * 128 + ((dq ^ (tq & 3)) << 2);
        wrd[dq] = wb + eq * 128 + ((dq ^ (eq & 3)) << 2);
    }

    // staging: 4 x-instrs + 4 w-instrs per 16-d chunk; global-side quad swizzle.
    // wave wv's chunk cc covers d = cc*256 + wv*16 + [0,16)  (interleaved slices:
    // waves 2k/2k+1 touch adjacent 64B halves of the same 128B line concurrently)
    const float* gxs[4]; const float* gws[4];
#pragma unroll
    for (int s = 0; s < 4; ++s) {
        int r  = s * 16 + (lane >> 2);          // token / expert row
        int ql = (lane & 3) ^ ((r >> 3) & 3);   // logical quad stored at this slot
        gxs[s] = x + (size_t)(tok0 + r) * D_DIM + wv * KCW + ql * 4;
        gws[s] = w + (size_t)r * D_DIM + wv * KCW + ql * 4;
    }

    float acc[64];
#pragma unroll
    for (int m = 0; m < 64; ++m) acc[m] = 0.f;

    for (int cc = 0; cc < NCHUNK; ++cc) {
#pragma unroll
        for (int s = 0; s < 4; ++s) {
            async_copy16(gxs[s], &xb[s * 256]);   // HW dest = uniform base + lane*16
            async_copy16(gws[s], &wb[s * 256]);
        }
#pragma unroll
        for (int s = 0; s < 4; ++s) { gxs[s] += 256; gws[s] += 256; }
        __builtin_amdgcn_s_waitcnt(0x0F70);       // vmcnt(0) only — wave-private drain

#pragma unroll
        for (int dq = 0; dq < 4; ++dq) {
#pragma unroll
            for (int h = 0; h < 2; ++h) {
                float2 xf[8], wf[8];
#pragma unroll
                for (int i = 0; i < 8; ++i)
                    xf[i] = *(const float2*)(xrd[dq] + i * 16 + h * 2);
#pragma unroll
                for (int j = 0; j < 8; ++j)
                    wf[j] = *(const float2*)(wrd[dq] + j * 16 + h * 2);
#pragma unroll
                for (int i = 0; i < 8; ++i)
#pragma unroll
                    for (int j = 0; j < 8; ++j) {
                        acc[i * 8 + j] = fmaf(xf[i].x, wf[j].x, acc[i * 8 + j]);
                        acc[i * 8 + j] = fmaf(xf[i].y, wf[j].y, acc[i * 8 + j]);
                    }
            }
        }
    }

    // ---- split-K tree reduction through LDS (regions k*4352 + lane*68) ----
    __syncthreads();                                        // B1
    if (wv >= 8) {
        float* r = &lds[(wv - 8) * 4352 + lane * 68];
#pragma unroll
        for (int m = 0; m < 16; ++m)
            *(float4*)(r + m * 4) = make_float4(acc[4*m], acc[4*m+1], acc[4*m+2], acc[4*m+3]);
    }
    __syncthreads();                                        // B2
    if (wv < 8) {
        const float* r = &lds[wv * 4352 + lane * 68];
#pragma unroll
        for (int m = 0; m < 16; ++m) {
            float4 v = *(const float4*)(r + m * 4);
            acc[4*m] += v.x; acc[4*m+1] += v.y; acc[4*m+2] += v.z; acc[4*m+3] += v.w;
        }
    }
    if (wv >= 4 && wv < 8) {                                // write own (just-read) region
        float* r = &lds[wv * 4352 + lane * 68];
#pragma unroll
        for (int m = 0; m < 16; ++m)
            *(float4*)(r + m * 4) = make_float4(acc[4*m], acc[4*m+1], acc[4*m+2], acc[4*m+3]);
    }
    __syncthreads();                                        // B3
    if (wv < 4) {
        const float* r = &lds[(wv + 4) * 4352 + lane * 68];
#pragma unroll
        for (int m = 0; m < 16; ++m) {
            float4 v = *(const float4*)(r + m * 4);
            acc[4*m] += v.x; acc[4*m+1] += v.y; acc[4*m+2] += v.z; acc[4*m+3] += v.w;
        }
    }
    if (wv >= 2 && wv < 4) {
        float* r = &lds[wv * 4352 + lane * 68];
#pragma unroll
        for (int m = 0; m < 16; ++m)
            *(float4*)(r + m * 4) = make_float4(acc[4*m], acc[4*m+1], acc[4*m+2], acc[4*m+3]);
    }
    __syncthreads();                                        // B4
    if (wv < 2) {
        const float* r = &lds[(wv + 2) * 4352 + lane * 68];
#pragma unroll
        for (int m = 0; m < 16; ++m) {
            float4 v = *(const float4*)(r + m * 4);
            acc[4*m] += v.x; acc[4*m+1] += v.y; acc[4*m+2] += v.z; acc[4*m+3] += v.w;
        }
    }
    if (wv == 1) {
        float* r = &lds[1 * 4352 + lane * 68];
#pragma unroll
        for (int m = 0; m < 16; ++m)
            *(float4*)(r + m * 4) = make_float4(acc[4*m], acc[4*m+1], acc[4*m+2], acc[4*m+3]);
    }
    __syncthreads();                                        // B5

    float* grid = &lds[2 * 4352];                           // 64 x 72 score grid
    if (wv == 0) {
        const float* r = &lds[1 * 4352 + lane * 68];
#pragma unroll
        for (int m = 0; m < 16; ++m) {
            float4 v = *(const float4*)(r + m * 4);
            acc[4*m] += v.x; acc[4*m+1] += v.y; acc[4*m+2] += v.z; acc[4*m+3] += v.w;
        }
        float gbv[8];
#pragma unroll
        for (int j = 0; j < 8; ++j) gbv[j] = gb[eq * 8 + j];
        float* sout = out + OUT_S_OFF;
#pragma unroll
        for (int i = 0; i < 8; ++i) {
            int t = tq * 8 + i;
            float sc[8];
#pragma unroll
            for (int j = 0; j < 8; ++j)
                sc[j] = 1.f / (1.f + expf(-acc[i * 8 + j])) + gbv[j];
            float* gp = grid + t * 72 + eq * 8;
            *(float4*)(gp)     = make_float4(sc[0], sc[1], sc[2], sc[3]);
            *(float4*)(gp + 4) = make_float4(sc[4], sc[5], sc[6], sc[7]);
            float* so = sout + (size_t)(tok0 + t) * NE + eq * 8;
            *(float4*)(so)     = make_float4(sc[0], sc[1], sc[2], sc[3]);
            *(float4*)(so + 4) = make_float4(sc[4], sc[5], sc[6], sc[7]);
        }
    }
    __syncthreads();                                        // B6

    // ---- fused top-8 (verified semantics: ties -> lower index), waves 0..3 ----
    if (tid < 256) {
        const int t = tid >> 2;       // local token
        const int q = tid & 3;        // quarter
        float v[16];
        const float4* sp = (const float4*)(grid + t * 72 + q * 16);
        float4 a = sp[0], b = sp[1], c = sp[2], d = sp[3];
        v[0] = a.x;  v[1] = a.y;  v[2] = a.z;  v[3] = a.w;
        v[4] = b.x;  v[5] = b.y;  v[6] = b.z;  v[7] = b.w;
        v[8] = c.x;  v[9] = c.y;  v[10] = c.z; v[11] = c.w;
        v[12] = d.x; v[13] = d.y; v[14] = d.z; v[15] = d.w;

        float kv[TK]; int ki[TK];
#pragma unroll
        for (int k = 0; k < TK; ++k) {
            float bv = v[0]; int bi = q * 16;
#pragma unroll
            for (int j = 1; j < 16; ++j) {
                bool gt = v[j] > bv;
                bv = gt ? v[j] : bv;
                bi = gt ? (q * 16 + j) : bi;
            }
#pragma unroll
            for (int off = 1; off < 4; off <<= 1) {
                float ov = __shfl_xor(bv, off);
                int   oi = __shfl_xor(bi, off);
                bool take = (ov > bv) || (ov == bv && oi < bi);
                bv = take ? ov : bv;
                bi = take ? oi : bi;
            }
            int lj = bi - q * 16;
#pragma unroll
            for (int j = 0; j < 16; ++j) v[j] = (j == lj) ? -3e38f : v[j];
            kv[k] = bv; ki[k] = bi;
        }

        if (q == 0) {
            float s = 0.f;
#pragma unroll
            for (int k = 0; k < TK; ++k) s += kv[k];
            float inv = 1.f / s;
            int tg = tok0 + t;
            float* ow = out + (size_t)tg * TK;
            float* oi = out + OUT_I_OFF + (size_t)tg * TK;
#pragma unroll
            for (int k = 0; k < TK; ++k) {
                ow[k] = kv[k] * inv;
                oi[k] = (float)ki[k];
            }
        }
    }
}

extern "C" void kernel_launch(void* const* d_in, const int* in_sizes, int n_in,
                              void* d_out, int out_size, void* d_ws, size_t ws_size,
                              hipStream_t stream) {
    const float* x  = (const float*)d_in[0];   // [4,4096,2048] fp32
    const float* w  = (const float*)d_in[1];   // [64,2048] fp32
    const float* gb = (const float*)d_in[2];   // [64] fp32
    float* out = (float*)d_out;
    (void)in_sizes; (void)n_in; (void)out_size; (void)d_ws; (void)ws_size;

    gate_fused<<<dim3(NTOK / TOKB), dim3(GT), 0, stream>>>(x, w, gb, out);
}